// Round 3
// baseline (1456.160 us; speedup 1.0000x reference)
//
#include <hip/hip_runtime.h>

#define N_IN   100000
#define N_OUT  400000
#define KK     8
#define PP     100000
#define C_IN   128
#define C_OUTC 64
#define C_SKIP 64
#define EPS_BN 1e-5f
#define WPAD   132   // padded LDS row stride (floats): 16B-aligned, bank-rotating

// ---------------------------------------------------------------------------
// Scatter: y[out_idx] += x[in_idx] @ W_deconv[k]
// blockIdx.y = k. W transposed in LDS (wt[c][i]) -> lane reads its column as
// ds_read_b128. x rows read as wave-uniform float4 VECTOR loads (VGPR indices,
// coalesced broadcast) -- NOT scalar loads (random rows thrash sL1).
// 8 pairs per wave-iteration.
// ---------------------------------------------------------------------------
__global__ __launch_bounds__(512) void scatter_kernel(
    const float* __restrict__ x, const float* __restrict__ Wd,
    const int* __restrict__ in_idx, const int* __restrict__ out_idx,
    float* __restrict__ y)
{
    __shared__ float wt[C_OUTC * WPAD];            // 33792 B
    const int k = blockIdx.y;
    {
        const float* __restrict__ Wk = Wd + (size_t)k * (C_IN * C_OUTC);
        for (int e = threadIdx.x; e < C_IN * C_OUTC; e += 512) {
            const int i = e >> 6, c = e & 63;      // coalesced global read
            wt[c * WPAD + i] = Wk[e];
        }
    }
    __syncthreads();

    const int lane = threadIdx.x & 63;
    const int wv = (int)((blockIdx.x * 512 + threadIdx.x) >> 6);   // stays VGPR
    const int nw = (int)gridDim.x * 8;
    const int* __restrict__ ii = in_idx + k * PP;
    const int* __restrict__ oi = out_idx + k * PP;
    const float* wrow = wt + lane * WPAD;

    for (int g = wv; g < PP / 8; g += nw) {
        const int q0 = g * 8;
        int ip[8], op[8];
        #pragma unroll
        for (int j = 0; j < 8; ++j) { ip[j] = ii[q0 + j]; op[j] = oi[q0 + j]; }
        const float4* __restrict__ xr[8];
        #pragma unroll
        for (int j = 0; j < 8; ++j) xr[j] = (const float4*)(x + (size_t)ip[j] * C_IN);

        float acc[8] = {0.f,0.f,0.f,0.f,0.f,0.f,0.f,0.f};
        #pragma unroll 4
        for (int iq = 0; iq < C_IN / 4; ++iq) {
            const float4 w4 = *(const float4*)(wrow + iq * 4);     // ds_read_b128
            #pragma unroll
            for (int j = 0; j < 8; ++j) {
                const float4 xv = xr[j][iq];                       // uniform vec load
                acc[j] = fmaf(xv.x, w4.x, acc[j]);
                acc[j] = fmaf(xv.y, w4.y, acc[j]);
                acc[j] = fmaf(xv.z, w4.z, acc[j]);
                acc[j] = fmaf(xv.w, w4.w, acc[j]);
            }
        }
        #pragma unroll
        for (int j = 0; j < 8; ++j)
            atomicAdd(&y[(size_t)op[j] * C_OUTC + lane], acc[j]);
    }
}

// ---------------------------------------------------------------------------
// Per-channel sum / sumsq over y (float4 per thread) -> stats[0:64] | [64:128]
// ---------------------------------------------------------------------------
__global__ __launch_bounds__(256) void stats_kernel(
    const float* __restrict__ y, float* __restrict__ stats)
{
    const int tid = threadIdx.x;
    const int cq  = tid & 15;                          // channel quad 0..15
    const int rid = (int)((blockIdx.x * 256 + tid) >> 4);
    const int nr  = (int)(gridDim.x * 256) >> 4;
    const float4* __restrict__ y4 = (const float4*)y;

    float sx=0,sy=0,sz=0,sw=0, qx=0,qy=0,qz=0,qw=0;
    for (int r = rid; r < N_OUT; r += nr) {
        const float4 v = y4[(size_t)r * 16 + cq];
        sx += v.x; sy += v.y; sz += v.z; sw += v.w;
        qx = fmaf(v.x, v.x, qx); qy = fmaf(v.y, v.y, qy);
        qz = fmaf(v.z, v.z, qz); qw = fmaf(v.w, v.w, qw);
    }
    __shared__ float ls[4 * 256];
    __shared__ float lq[4 * 256];
    ls[0*256+tid]=sx; ls[1*256+tid]=sy; ls[2*256+tid]=sz; ls[3*256+tid]=sw;
    lq[0*256+tid]=qx; lq[1*256+tid]=qy; lq[2*256+tid]=qz; lq[3*256+tid]=qw;
    __syncthreads();
    for (int off = 128; off >= 16; off >>= 1) {
        if (tid < off) {
            #pragma unroll
            for (int c = 0; c < 4; ++c) {
                ls[c*256+tid] += ls[c*256+tid+off];
                lq[c*256+tid] += lq[c*256+tid+off];
            }
        }
        __syncthreads();
    }
    if (tid < 16) {
        #pragma unroll
        for (int c = 0; c < 4; ++c) {
            atomicAdd(&stats[tid * 4 + c],           ls[c*256+tid]);
            atomicAdd(&stats[C_OUTC + tid * 4 + c],  lq[c*256+tid]);
        }
    }
}

// ---------------------------------------------------------------------------
// Fold gamma/beta/mean/var into per-channel scale & shift.
// ---------------------------------------------------------------------------
__global__ void finalize_kernel(const float* __restrict__ stats,
                                const float* __restrict__ gamma,
                                const float* __restrict__ beta,
                                float* __restrict__ sc)
{
    const int c = threadIdx.x;                 // 64 threads
    const float inv_n = 1.0f / (float)N_OUT;
    const float mean  = stats[c] * inv_n;
    const float var   = stats[C_OUTC + c] * inv_n - mean * mean;
    const float s     = gamma[c] * rsqrtf(var + EPS_BN);
    sc[c]          = s;
    sc[C_OUTC + c] = beta[c] - mean * s;
}

// ---------------------------------------------------------------------------
// Fused BN + ReLU + concat + linear, in-place on y.
// out[n] = relu(bn(y[n])) @ Wf[0:64] + skip[n] @ Wf[64:128]
// Wf transposed in LDS; BN applied inline on the uniform y loads.
// Each wave fully reads its 8 rows before overwriting them; rows are
// wave-private so no cross-wave hazard.
// ---------------------------------------------------------------------------
__global__ __launch_bounds__(512) void fuse_kernel(
    float* __restrict__ y, const float* __restrict__ skip,
    const float* __restrict__ Wf, const float* __restrict__ sc)
{
    __shared__ float wt[C_OUTC * WPAD];            // wt[c][i], i = 0..127
    __shared__ float scl[2 * C_OUTC];
    for (int e = threadIdx.x; e < (C_OUTC + C_SKIP) * C_OUTC; e += 512) {
        const int i = e >> 6, c = e & 63;
        wt[c * WPAD + i] = Wf[e];
    }
    if (threadIdx.x < 2 * C_OUTC) scl[threadIdx.x] = sc[threadIdx.x];
    __syncthreads();

    const int lane = threadIdx.x & 63;
    const int wv = (int)((blockIdx.x * 512 + threadIdx.x) >> 6);
    const int nw = (int)gridDim.x * 8;
    const float* wrow = wt + lane * WPAD;

    for (int g = wv; g < N_OUT / 8; g += nw) {
        const size_t r0 = (size_t)g * 8;
        const float4* __restrict__ yr = (const float4*)(y + r0 * C_OUTC);
        const float4* __restrict__ sr = (const float4*)(skip + r0 * C_SKIP);

        float acc[8] = {0.f,0.f,0.f,0.f,0.f,0.f,0.f,0.f};
        // ---- y half (input channels 0..63) with inline BN+ReLU ----
        #pragma unroll 4
        for (int iq = 0; iq < 16; ++iq) {
            const float4 w4 = *(const float4*)(wrow + iq * 4);
            const float4 s4 = *(const float4*)(scl + iq * 4);
            const float4 b4 = *(const float4*)(scl + C_OUTC + iq * 4);
            #pragma unroll
            for (int j = 0; j < 8; ++j) {
                float4 v = yr[j * 16 + iq];
                v.x = fmaxf(fmaf(v.x, s4.x, b4.x), 0.f);
                v.y = fmaxf(fmaf(v.y, s4.y, b4.y), 0.f);
                v.z = fmaxf(fmaf(v.z, s4.z, b4.z), 0.f);
                v.w = fmaxf(fmaf(v.w, s4.w, b4.w), 0.f);
                acc[j] = fmaf(v.x, w4.x, acc[j]);
                acc[j] = fmaf(v.y, w4.y, acc[j]);
                acc[j] = fmaf(v.z, w4.z, acc[j]);
                acc[j] = fmaf(v.w, w4.w, acc[j]);
            }
        }
        // ---- skip half (input channels 64..127) ----
        #pragma unroll 4
        for (int iq = 0; iq < 16; ++iq) {
            const float4 w4 = *(const float4*)(wrow + C_OUTC + iq * 4);
            #pragma unroll
            for (int j = 0; j < 8; ++j) {
                const float4 v = sr[j * 16 + iq];
                acc[j] = fmaf(v.x, w4.x, acc[j]);
                acc[j] = fmaf(v.y, w4.y, acc[j]);
                acc[j] = fmaf(v.z, w4.z, acc[j]);
                acc[j] = fmaf(v.w, w4.w, acc[j]);
            }
        }
        #pragma unroll
        for (int j = 0; j < 8; ++j)
            y[(r0 + j) * C_OUTC + lane] = acc[j];
    }
}

// ---------------------------------------------------------------------------
extern "C" void kernel_launch(void* const* d_in, const int* in_sizes, int n_in,
                              void* d_out, int out_size, void* d_ws, size_t ws_size,
                              hipStream_t stream)
{
    const float* x      = (const float*)d_in[0];
    const float* skip   = (const float*)d_in[1];
    const float* Wd     = (const float*)d_in[2];
    const float* gamma  = (const float*)d_in[3];
    const float* beta   = (const float*)d_in[4];
    const float* Wf     = (const float*)d_in[5];
    const int*   in_idx  = (const int*)d_in[6];
    const int*   out_idx = (const int*)d_in[7];

    float* y     = (float*)d_out;            // y lives in d_out (same shape)
    float* stats = (float*)d_ws;             // 128 floats: sum | sumsq
    float* sc    = stats + 128;              // 128 floats: scale | shift

    hipMemsetAsync(d_out, 0, (size_t)N_OUT * C_OUTC * sizeof(float), stream);
    hipMemsetAsync(d_ws, 0, 128 * sizeof(float), stream);

    dim3 sgrid(128, KK, 1);                  // 1024 blocks, blockIdx.y = k
    scatter_kernel<<<sgrid, 512, 0, stream>>>(x, Wd, in_idx, out_idx, y);
    stats_kernel<<<2048, 256, 0, stream>>>(y, stats);
    finalize_kernel<<<1, 64, 0, stream>>>(stats, gamma, beta, sc);
    fuse_kernel<<<1024, 512, 0, stream>>>(y, skip, Wf, sc);
}

// Round 4
// 1207.530 us; speedup vs baseline: 1.2059x; 1.2059x over previous
//
#include <hip/hip_runtime.h>

#define N_IN   100000
#define N_OUT  400000
#define KK     8
#define PP     100000
#define C_IN   128
#define C_OUTC 64
#define C_SKIP 64
#define EPS_BN 1e-5f

// ---------------------------------------------------------------------------
// Scatter: y[out_idx] += x[in_idx] @ W_deconv[k]
// blockIdx.y = k. W staged in LDS as [i][c] (b32 reads: consecutive lanes ->
// consecutive banks, 2-way aliasing = free). x rows read as per-lane-uniform
// float4 VECTOR loads (VGPR indices -> coalesced broadcast, deep vmcnt queue).
// 8 pairs per wave-iteration amortize the weight ds_reads 8x.
// ---------------------------------------------------------------------------
__global__ __launch_bounds__(512) void scatter_kernel(
    const float* __restrict__ x, const float* __restrict__ Wd,
    const int* __restrict__ in_idx, const int* __restrict__ out_idx,
    float* __restrict__ y)
{
    __shared__ float wlds[C_IN * C_OUTC];          // 32 KB, [i][c]
    const int k = blockIdx.y;
    {
        const float4* src = (const float4*)(Wd + (size_t)k * (C_IN * C_OUTC));
        for (int t = threadIdx.x; t < (C_IN * C_OUTC) / 4; t += 512)
            ((float4*)wlds)[t] = src[t];
    }
    __syncthreads();

    const int lane = threadIdx.x & 63;
    const int wv = (int)((blockIdx.x * 512 + threadIdx.x) >> 6);   // VGPR wave id
    const int nw = (int)gridDim.x * 8;
    const int4* __restrict__ ii4 = (const int4*)(in_idx + k * PP);
    const int4* __restrict__ oi4 = (const int4*)(out_idx + k * PP);

    for (int g = wv; g < PP / 8; g += nw) {
        const int4 ia = ii4[2 * g], ib = ii4[2 * g + 1];
        const int4 oa = oi4[2 * g], ob = oi4[2 * g + 1];
        const float4* __restrict__ xr[8];
        xr[0] = (const float4*)(x + (size_t)ia.x * C_IN);
        xr[1] = (const float4*)(x + (size_t)ia.y * C_IN);
        xr[2] = (const float4*)(x + (size_t)ia.z * C_IN);
        xr[3] = (const float4*)(x + (size_t)ia.w * C_IN);
        xr[4] = (const float4*)(x + (size_t)ib.x * C_IN);
        xr[5] = (const float4*)(x + (size_t)ib.y * C_IN);
        xr[6] = (const float4*)(x + (size_t)ib.z * C_IN);
        xr[7] = (const float4*)(x + (size_t)ib.w * C_IN);

        float acc[8] = {0.f,0.f,0.f,0.f,0.f,0.f,0.f,0.f};
        #pragma unroll 4
        for (int iq = 0; iq < C_IN / 4; ++iq) {
            const float w0 = wlds[(iq * 4 + 0) * C_OUTC + lane];
            const float w1 = wlds[(iq * 4 + 1) * C_OUTC + lane];
            const float w2 = wlds[(iq * 4 + 2) * C_OUTC + lane];
            const float w3 = wlds[(iq * 4 + 3) * C_OUTC + lane];
            #pragma unroll
            for (int j = 0; j < 8; ++j) {
                const float4 v = xr[j][iq];
                acc[j] = fmaf(v.x, w0, acc[j]);
                acc[j] = fmaf(v.y, w1, acc[j]);
                acc[j] = fmaf(v.z, w2, acc[j]);
                acc[j] = fmaf(v.w, w3, acc[j]);
            }
        }
        atomicAdd(&y[(size_t)oa.x * C_OUTC + lane], acc[0]);
        atomicAdd(&y[(size_t)oa.y * C_OUTC + lane], acc[1]);
        atomicAdd(&y[(size_t)oa.z * C_OUTC + lane], acc[2]);
        atomicAdd(&y[(size_t)oa.w * C_OUTC + lane], acc[3]);
        atomicAdd(&y[(size_t)ob.x * C_OUTC + lane], acc[4]);
        atomicAdd(&y[(size_t)ob.y * C_OUTC + lane], acc[5]);
        atomicAdd(&y[(size_t)ob.z * C_OUTC + lane], acc[6]);
        atomicAdd(&y[(size_t)ob.w * C_OUTC + lane], acc[7]);
    }
}

// ---------------------------------------------------------------------------
// Per-channel sum / sumsq over y (float4 per thread) -> stats[0:64] | [64:128]
// ---------------------------------------------------------------------------
__global__ __launch_bounds__(256) void stats_kernel(
    const float* __restrict__ y, float* __restrict__ stats)
{
    const int tid = threadIdx.x;
    const int cq  = tid & 15;                          // channel quad 0..15
    const int rid = (int)((blockIdx.x * 256 + tid) >> 4);
    const int nr  = (int)(gridDim.x * 256) >> 4;
    const float4* __restrict__ y4 = (const float4*)y;

    float sx=0,sy=0,sz=0,sw=0, qx=0,qy=0,qz=0,qw=0;
    for (int r = rid; r < N_OUT; r += nr) {
        const float4 v = y4[(size_t)r * 16 + cq];
        sx += v.x; sy += v.y; sz += v.z; sw += v.w;
        qx = fmaf(v.x, v.x, qx); qy = fmaf(v.y, v.y, qy);
        qz = fmaf(v.z, v.z, qz); qw = fmaf(v.w, v.w, qw);
    }
    __shared__ float ls[4 * 256];
    __shared__ float lq[4 * 256];
    ls[0*256+tid]=sx; ls[1*256+tid]=sy; ls[2*256+tid]=sz; ls[3*256+tid]=sw;
    lq[0*256+tid]=qx; lq[1*256+tid]=qy; lq[2*256+tid]=qz; lq[3*256+tid]=qw;
    __syncthreads();
    for (int off = 128; off >= 16; off >>= 1) {
        if (tid < off) {
            #pragma unroll
            for (int c = 0; c < 4; ++c) {
                ls[c*256+tid] += ls[c*256+tid+off];
                lq[c*256+tid] += lq[c*256+tid+off];
            }
        }
        __syncthreads();
    }
    if (tid < 16) {
        #pragma unroll
        for (int c = 0; c < 4; ++c) {
            atomicAdd(&stats[tid * 4 + c],           ls[c*256+tid]);
            atomicAdd(&stats[C_OUTC + tid * 4 + c],  lq[c*256+tid]);
        }
    }
}

// ---------------------------------------------------------------------------
// Fold BN into fuse-friendly constants.
//  s[i]   = gamma*rsqrt(var+eps)          (sc[0:64])   -> scales Wf rows
//  nb[i]  = -(beta - mean*s)/s            (sc[64:128]) -> relu(y*s+b) = s*(max(y,nb')+...)
//  bias[c]= sum_i b_i * Wf[i][c]          (sc[128:192])-> accumulator seed
// Derivation: relu(y*s+b) @ W = max(y, -b/s) @ (diag(s)W) + (b @ W), s > 0.
// ---------------------------------------------------------------------------
__global__ void finalize_kernel(const float* __restrict__ stats,
                                const float* __restrict__ gamma,
                                const float* __restrict__ beta,
                                const float* __restrict__ Wf,
                                float* __restrict__ sc)
{
    __shared__ float bsh[C_OUTC];
    const int c = threadIdx.x;                 // 64 threads
    const float inv_n = 1.0f / (float)N_OUT;
    const float mean  = stats[c] * inv_n;
    const float var   = stats[C_OUTC + c] * inv_n - mean * mean;
    const float s     = gamma[c] * rsqrtf(var + EPS_BN);
    const float b     = beta[c] - mean * s;
    sc[c]            = s;
    sc[C_OUTC + c]   = -b / s;
    bsh[c] = b;
    __syncthreads();
    float acc = 0.f;
    for (int i = 0; i < C_OUTC; ++i)
        acc = fmaf(bsh[i], Wf[i * C_OUTC + c], acc);
    sc[2 * C_OUTC + c] = acc;
}

// ---------------------------------------------------------------------------
// Fused BN+ReLU+concat+linear, in-place on y.
// Wf staged in LDS with BN scale pre-multiplied into the y-half rows;
// accumulator seeded with the BN bias term; inner loop costs only one extra
// v_max per y element. Rows via scalar loads (sequential -> sL1-friendly).
// Each wave fully reads its 8 rows before overwriting them.
// ---------------------------------------------------------------------------
__global__ __launch_bounds__(512) void fuse_kernel(
    float* __restrict__ y, const float* __restrict__ skip,
    const float* __restrict__ Wf, const float* __restrict__ sc)
{
    __shared__ float wlds[C_IN * C_OUTC];          // [i][c], y-half pre-scaled
    __shared__ float nb[C_OUTC];
    for (int e = threadIdx.x; e < C_IN * C_OUTC; e += 512) {
        const int i = e >> 6;
        const float w = Wf[e];
        wlds[e] = (i < C_OUTC) ? w * sc[i] : w;
    }
    if (threadIdx.x < C_OUTC) nb[threadIdx.x] = sc[C_OUTC + threadIdx.x];
    __syncthreads();

    const int lane = threadIdx.x & 63;
    int wv = (int)((blockIdx.x * 512 + threadIdx.x) >> 6);
    wv = __builtin_amdgcn_readfirstlane(wv);       // SGPR wave id -> s_load rows
    const int nw = (int)gridDim.x * 8;
    const float bias0 = sc[2 * C_OUTC + lane];

    for (int g = wv; g < N_OUT / 8; g += nw) {
        const float* __restrict__ yr = y    + (size_t)g * 8 * C_OUTC;
        const float* __restrict__ sr = skip + (size_t)g * 8 * C_SKIP;

        float acc[8];
        #pragma unroll
        for (int r = 0; r < 8; ++r) acc[r] = bias0;

        #pragma unroll 8
        for (int i = 0; i < C_OUTC; ++i) {
            const float w = wlds[i * C_OUTC + lane];
            const float t = nb[i];
            #pragma unroll
            for (int r = 0; r < 8; ++r)
                acc[r] = fmaf(fmaxf(yr[r * C_OUTC + i], t), w, acc[r]);
        }
        #pragma unroll 8
        for (int i = 0; i < C_SKIP; ++i) {
            const float w = wlds[(C_OUTC + i) * C_OUTC + lane];
            #pragma unroll
            for (int r = 0; r < 8; ++r)
                acc[r] = fmaf(sr[r * C_SKIP + i], w, acc[r]);
        }
        #pragma unroll
        for (int r = 0; r < 8; ++r)
            y[((size_t)g * 8 + r) * C_OUTC + lane] = acc[r];
    }
}

// ---------------------------------------------------------------------------
extern "C" void kernel_launch(void* const* d_in, const int* in_sizes, int n_in,
                              void* d_out, int out_size, void* d_ws, size_t ws_size,
                              hipStream_t stream)
{
    const float* x      = (const float*)d_in[0];
    const float* skip   = (const float*)d_in[1];
    const float* Wd     = (const float*)d_in[2];
    const float* gamma  = (const float*)d_in[3];
    const float* beta   = (const float*)d_in[4];
    const float* Wf     = (const float*)d_in[5];
    const int*   in_idx  = (const int*)d_in[6];
    const int*   out_idx = (const int*)d_in[7];

    float* y     = (float*)d_out;            // y lives in d_out (same shape)
    float* stats = (float*)d_ws;             // 128 floats: sum | sumsq
    float* sc    = stats + 128;              // 192 floats: s | -b/s | bias

    hipMemsetAsync(d_out, 0, (size_t)N_OUT * C_OUTC * sizeof(float), stream);
    hipMemsetAsync(d_ws, 0, 128 * sizeof(float), stream);

    dim3 sgrid(128, KK, 1);                  // 1024 blocks, blockIdx.y = k
    scatter_kernel<<<sgrid, 512, 0, stream>>>(x, Wd, in_idx, out_idx, y);
    stats_kernel<<<2048, 256, 0, stream>>>(y, stats);
    finalize_kernel<<<1, 64, 0, stream>>>(stats, gamma, beta, Wf, sc);
    fuse_kernel<<<1024, 512, 0, stream>>>(y, skip, Wf, sc);
}